// Round 16
// baseline (746.284 us; speedup 1.0000x reference)
//
#include <hip/hip_runtime.h>
#include <hip/hip_bf16.h>

typedef unsigned short u16;
typedef unsigned int u32;
typedef __attribute__((ext_vector_type(4))) u32 u32x4;
typedef __attribute__((ext_vector_type(2))) u32 u32x2;
typedef __attribute__((ext_vector_type(8))) __bf16 bf16x8;
typedef __attribute__((ext_vector_type(4))) float f32x4;
typedef __attribute__((ext_vector_type(4))) short short4v;

#define HW 65536
#define MFMA32(a, b, c) __builtin_amdgcn_mfma_f32_16x16x32_bf16((a), (b), (c), 0, 0, 0)

__device__ __forceinline__ u16 f2bf(float f){
  union { u32 i; float f; } v; v.f = f;
  u32 r = v.i + 0x7fffu + ((v.i >> 16) & 1u);
  return (u16)(r >> 16);
}
__device__ __forceinline__ u32 pkbf(float a, float b){
  __bf16 lo = (__bf16)a, hi = (__bf16)b;
  u16 ulo = __builtin_bit_cast(u16, lo);
  u16 uhi = __builtin_bit_cast(u16, hi);
  return (u32)ulo | ((u32)uhi << 16);
}
__device__ __forceinline__ float rcpf(float x){
#if __has_builtin(__builtin_amdgcn_rcpf)
  return __builtin_amdgcn_rcpf(x);
#else
  return 1.0f / x;
#endif
}
__device__ __forceinline__ float gelu_tanh(float v){
  float t = v * v;
  float u = fmaf(0.044715f * t, v, v);
  float z = 1.5957691216057308f * u;
  float e = __expf(-z);
  return v * rcpf(1.0f + e);
}

__device__ __forceinline__ f32x4 mfma16bf16(short4v a, short4v b, f32x4 c){
#if __has_builtin(__builtin_amdgcn_mfma_f32_16x16x16bf16_1k)
  return __builtin_amdgcn_mfma_f32_16x16x16bf16_1k(a, b, c, 0, 0, 0);
#else
  f32x4 d;
  asm volatile("v_mfma_f32_16x16x16_bf16 %0, %1, %2, %3"
               : "=v"(d) : "v"(a), "v"(b), "v"(c));
  return d;
#endif
}

// ---- pack weights into DENSE (1KB) bf16 MFMA A-fragment tiles --------------
// LN folds: qkv tiles carry n1w (q rows also carry hd^-0.5); w1 carries n2w.
// Folded biases (f32): bq[o] = (qkvb[o] + Wqkv.n1b)·qs, b1p[h] = b1[h] + W1.n2b
__global__ __launch_bounds__(256) void k_pack(
    const float* __restrict__ qkvw, const float* __restrict__ projw,
    const float* __restrict__ w1, const float* __restrict__ w2,
    const float* __restrict__ n1w, const float* __restrict__ n1b,
    const float* __restrict__ n2w, const float* __restrict__ n2b,
    const float* __restrict__ qkvb, const float* __restrict__ b1,
    u16* __restrict__ wf)
{
  const float S = 0.17677669529663687f;   // HEAD_DIM^-0.5
  int tile = blockIdx.x;
  int t = threadIdx.x;
  float* bias = (float*)(wf + 196608);
  if (tile >= 384){
    if (tile < 386){
      int o = (tile - 384) * 256 + t;
      if (o < 384){
        float s = qkvb[o];
        for (int c = 0; c < 128; ++c) s = fmaf(qkvw[(size_t)o * 128 + c], n1b[c], s);
        bias[o] = s * (o < 128 ? S : 1.f);
      }
    } else {
      int h = (tile - 386) * 256 + t;
      float s = b1[h];
      for (int c = 0; c < 128; ++c) s = fmaf(w1[(size_t)h * 128 + c], n2b[c], s);
      bias[384 + h] = s;
    }
    return;
  }
  int l = t >> 1, half = t & 1;
  if (l >= 64) return;
  int lg = l >> 4;
  if (tile >= 256){
    int ti = tile - 256;
    int hp = ti >> 3, m = ti & 7;
    int row = m * 16 + (l & 15);
    u16 o[4];
    #pragma unroll
    for (int j = 0; j < 4; ++j){
      int s = half * 4 + j;
      int kloc = (s < 4) ? (4 * lg + s) : (16 + 4 * lg + (s - 4));
      o[j] = f2bf(w2[(size_t)row * 512 + hp * 32 + kloc]);
    }
    u32x2 v; v[0] = (u32)o[0] | ((u32)o[1] << 16); v[1] = (u32)o[2] | ((u32)o[3] << 16);
    *(u32x2*)(wf + 131072 + ti * 512 + l * 8 + half * 4) = v;
    return;
  }
  const float* W; int base, ti; int mode;
  if (tile < 96)       { W = qkvw; base = 0;     ti = tile;      mode = 0; }
  else if (tile < 128) { W = projw; base = 49152; ti = tile - 96; mode = 1; }
  else                 { W = w1;   base = 65536; ti = tile - 128; mode = 2; }
  int mt = ti / 4, kt = ti % 4;
  int r0 = half * 4;
  int m = mt * 16 + (l & 15);
  int kb = kt * 32 + 8 * lg + r0;
  u16 o[4];
  #pragma unroll
  for (int j = 0; j < 4; ++j){
    float wv = W[(size_t)m * 128 + kb + j];
    if (mode == 0) wv *= n1w[kb + j] * (m < 128 ? S : 1.f);
    if (mode == 2) wv *= n2w[kb + j];
    o[j] = f2bf(wv);
  }
  u32x2 v; v[0] = (u32)o[0] | ((u32)o[1] << 16); v[1] = (u32)o[2] | ((u32)o[3] << 16);
  *(u32x2*)(wf + base + ti * 512 + l * 8 + r0) = v;
}

// ---- kernel 1: channel-LN + QKV GEMM; 128-px blocks, staged weights --------
__global__ __launch_bounds__(256, 4) void k_ln_qkv(
    const float* __restrict__ x, const u16* __restrict__ wfq,
    const float* __restrict__ bq, u16* __restrict__ qkvp)
{
  __shared__ __align__(16) char smem[32768];   // bufA @0, bufB @16384
  const int t = threadIdx.x;
  const int w = t >> 6, l = t & 63, lg = l >> 4, ln = l & 15;
  const int P0 = blockIdx.x * 128;
  const int b = P0 >> 16;
  const int pix0 = P0 & 65535;

  auto stage8k = [&](const u16* gsrc, int ldsoff){
    const char* g = (const char*)gsrc;
    int base = w * 2048;
    #pragma unroll
    for (int i = 0; i < 2; ++i){
      int off = base + i * 1024;
      __builtin_amdgcn_global_load_lds(
        (const u32 __attribute__((address_space(1)))*)(g + off + l * 16),
        (u32 __attribute__((address_space(3)))*)(smem + ldsoff + off),
        16, 0, 0);
    }
  };

  stage8k(wfq, 0);
  stage8k(wfq + 4096, 8192);

  const int pA = w * 32 + ln, pB = pA + 16;

  float xA[8][4], xB[8][4];
  float sA = 0.f, s2A = 0.f, sB = 0.f, s2B = 0.f;
  #pragma unroll
  for (int m = 0; m < 8; ++m){
    int c0 = m * 16 + 4 * lg;
    size_t base = ((size_t)(b * 128 + c0)) * HW + pix0 + pA;
    #pragma unroll
    for (int r = 0; r < 4; ++r){
      float vA = x[base + (size_t)r * HW];
      float vB = x[base + 16 + (size_t)r * HW];
      xA[m][r] = vA; xB[m][r] = vB;
      sA += vA; s2A = fmaf(vA, vA, s2A);
      sB += vB; s2B = fmaf(vB, vB, s2B);
    }
  }
  sA  += __shfl_xor(sA, 16);  sA  += __shfl_xor(sA, 32);
  s2A += __shfl_xor(s2A, 16); s2A += __shfl_xor(s2A, 32);
  sB  += __shfl_xor(sB, 16);  sB  += __shfl_xor(sB, 32);
  s2B += __shfl_xor(s2B, 16); s2B += __shfl_xor(s2B, 32);
  float muA = sA * 0.0078125f;
  float rsA = rsqrtf(s2A * 0.0078125f - muA * muA + 1e-5f);
  float muB = sB * 0.0078125f;
  float rsB = rsqrtf(s2B * 0.0078125f - muB * muB + 1e-5f);

  bf16x8 bbA[4], bbB[4];
  {
    char* wbase = smem + 16384 + w * 4096;
    #pragma unroll
    for (int m = 0; m < 8; ++m){
      int g8 = 2 * m + (lg >> 1);
      u32x2 pk;
      pk[0] = pkbf((xA[m][0]-muA)*rsA, (xA[m][1]-muA)*rsA);
      pk[1] = pkbf((xA[m][2]-muA)*rsA, (xA[m][3]-muA)*rsA);
      *(u32x2*)(wbase + ln * 256 + ((g8 ^ (ln & 7)) << 4) + ((lg & 1) << 3)) = pk;
    }
    #pragma unroll
    for (int kt = 0; kt < 4; ++kt)
      bbA[kt] = *(const bf16x8*)(wbase + ln * 256 + (((kt*4 + lg) ^ (ln & 7)) << 4));
    #pragma unroll
    for (int m = 0; m < 8; ++m){
      int g8 = 2 * m + (lg >> 1);
      u32x2 pk;
      pk[0] = pkbf((xB[m][0]-muB)*rsB, (xB[m][1]-muB)*rsB);
      pk[1] = pkbf((xB[m][2]-muB)*rsB, (xB[m][3]-muB)*rsB);
      *(u32x2*)(wbase + ln * 256 + ((g8 ^ (ln & 7)) << 4) + ((lg & 1) << 3)) = pk;
    }
    #pragma unroll
    for (int kt = 0; kt < 4; ++kt)
      bbB[kt] = *(const bf16x8*)(wbase + ln * 256 + (((kt*4 + lg) ^ (ln & 7)) << 4));
  }
  __syncthreads();

  for (int c = 0; c < 6; ++c){
    const int cur = (c & 1) ? 16384 : 0;
    if (c < 5){
      const int nxt = cur ^ 16384;
      stage8k(wfq + (c + 1) * 8192, nxt);
      stage8k(wfq + (c + 1) * 8192 + 4096, nxt + 8192);
    }
    #pragma unroll
    for (int mt = 0; mt < 4; ++mt){
      f32x4 dA = (f32x4)(0.f), dB = (f32x4)(0.f);
      #pragma unroll
      for (int kt = 0; kt < 4; ++kt){
        bf16x8 a = *(const bf16x8*)(smem + cur + ((mt*4 + kt) << 10) + l * 16);
        dA = MFMA32(a, bbA[kt], dA);
        dB = MFMA32(a, bbB[kt], dB);
      }
      int o0 = c * 64 + mt * 16 + 4 * lg;
      f32x4 bqv = *(const f32x4*)(bq + o0);
      u32x2 vA, vB;
      vA[0] = pkbf(dA[0]+bqv[0], dA[1]+bqv[1]);
      vA[1] = pkbf(dA[2]+bqv[2], dA[3]+bqv[3]);
      vB[0] = pkbf(dB[0]+bqv[0], dB[1]+bqv[1]);
      vB[1] = pkbf(dB[2]+bqv[2], dB[3]+bqv[3]);
      u16* plane = qkvp + (size_t)(o0 >> 7) * 67108864ull;
      int hh = (o0 >> 5) & 3;
      int sub = o0 & 31;
      size_t pbase = ((size_t)(b * 4 + hh)) * 65536 + pix0;
      *(u32x2*)(plane + (pbase + pA) * 32 + sub) = vA;
      *(u32x2*)(plane + (pbase + pB) * 32 + sub) = vB;
    }
    if (c < 5) __syncthreads();
  }
}

// ---- kernel 2: 7x7 local attention via MFMA; 16x8 tiles (3 blocks/CU) ------
__global__ __launch_bounds__(256, 3) void k_attn(
    u16* qbuf, const u16* __restrict__ kbuf, const u16* __restrict__ vbuf)
{
  __shared__ __align__(16) u16 Klds[4 * 320 * 8];    // [chgrp][pix 14x22 -> 320][8ch]
  __shared__ __align__(16) u16 VT[32 * 344 + 8];     // [ch][14 rows x 24 pad, stride 344]
  const int t = threadIdx.x;
  const int blk = ((blockIdx.x & 7) << 11) | (blockIdx.x >> 3);
  const int tx16 = blk & 15, ty = (blk >> 4) & 31;
  const int h = (blk >> 9) & 3, b = blk >> 11;
  const int y0 = ty * 8, x0 = tx16 * 16;
  const int bh = b * 4 + h;
  const u16* kg = kbuf + (size_t)bh * 65536 * 32;
  const u16* vg = vbuf + (size_t)bh * 65536 * 32;

  for (int i = t; i < 1377; i += 256) ((u32x4*)VT)[i] = (u32x4){0u,0u,0u,0u};
  __syncthreads();

  for (int pix = t; pix < 308; pix += 256){
    int yy = pix / 22, xx = pix - yy * 22;
    int gy = y0 + yy - 3, gx = x0 + xx - 3;
    bool ok = (gy >= 0 && gy < 256 && gx >= 0 && gx < 256);
    u32x4 kv[4], vv[4];
    #pragma unroll
    for (int j = 0; j < 4; ++j){ kv[j] = (u32x4){0u,0u,0u,0u}; vv[j] = (u32x4){0u,0u,0u,0u}; }
    if (ok){
      size_t gb = ((size_t)(gy * 256 + gx)) * 32;
      #pragma unroll
      for (int j = 0; j < 4; ++j){
        kv[j] = *(const u32x4*)(kg + gb + j * 8);
        vv[j] = *(const u32x4*)(vg + gb + j * 8);
      }
    }
    #pragma unroll
    for (int j = 0; j < 4; ++j)
      *(u32x4*)(Klds + (j * 320 + pix) * 8) = kv[j];
    int vb = yy * 24 + xx;
    #pragma unroll
    for (int j = 0; j < 4; ++j)
      #pragma unroll
      for (int ww = 0; ww < 4; ++ww){
        int c = j * 8 + ww * 2;
        VT[(c    ) * 344 + vb] = (u16)(vv[j][ww] & 0xffffu);
        VT[(c + 1) * 344 + vb] = (u16)(vv[j][ww] >> 16);
      }
  }
  __syncthreads();

  const int l = t & 63, w = t >> 6;
  const int ln = l & 15, g = l >> 4;

  bool mk[2][4];
  #pragma unroll
  for (int sl = 0; sl < 2; ++sl)
    #pragma unroll
    for (int r = 0; r < 4; ++r)
      mk[sl][r] = ((unsigned)(sl * 16 + g * 4 + r - ln)) <= 6u;

  for (int rt = 0; rt < 2; ++rt){
    int yl = rt * 4 + w;
    int qpix = (y0 + yl) * 256 + x0 + ln;
    u16* qp = qbuf + ((size_t)bh * 65536 + qpix) * 32;
    bf16x8 qf = *(const bf16x8*)(qp + g * 8);

    f32x4 S[7][2];
    #pragma unroll
    for (int oi = 0; oi < 7; ++oi){
      int rowb = (yl + oi) * 22;
      #pragma unroll
      for (int sl = 0; sl < 2; ++sl){
        bf16x8 kf = *(const bf16x8*)(Klds + (g * 320 + rowb + sl * 16 + ln) * 8);
        f32x4 z = (f32x4)(0.f);
        S[oi][sl] = MFMA32(kf, qf, z);
      }
    }
    float m = -3e38f;
    #pragma unroll
    for (int oi = 0; oi < 7; ++oi)
      #pragma unroll
      for (int sl = 0; sl < 2; ++sl)
        #pragma unroll
        for (int r = 0; r < 4; ++r){
          float v = mk[sl][r] ? S[oi][sl][r] : -3e38f;
          S[oi][sl][r] = v;
          m = fmaxf(m, v);
        }
    m = fmaxf(m, __shfl_xor(m, 16));
    m = fmaxf(m, __shfl_xor(m, 32));
    float sum = 0.f;
    #pragma unroll
    for (int oi = 0; oi < 7; ++oi)
      #pragma unroll
      for (int sl = 0; sl < 2; ++sl)
        #pragma unroll
        for (int r = 0; r < 4; ++r){
          float e = __expf(S[oi][sl][r] - m);
          S[oi][sl][r] = e;
          sum += e;
        }
    sum += __shfl_xor(sum, 16);
    sum += __shfl_xor(sum, 32);
    float inv = rcpf(sum);

    short4v P[7][2];
    #pragma unroll
    for (int oi = 0; oi < 7; ++oi)
      #pragma unroll
      for (int sl = 0; sl < 2; ++sl){
        union { u32x2 u; short4v s; } cv;
        cv.u[0] = pkbf(S[oi][sl][0], S[oi][sl][1]);
        cv.u[1] = pkbf(S[oi][sl][2], S[oi][sl][3]);
        P[oi][sl] = cv.s;
      }

    f32x4 O0 = (f32x4)(0.f), O1 = (f32x4)(0.f);
    #pragma unroll
    for (int oi = 0; oi < 7; ++oi){
      int rowE = (yl + oi) * 24;
      #pragma unroll
      for (int sl = 0; sl < 2; ++sl){
        int xb = rowE + sl * 16 + 4 * g;
        short4v v0 = *(const short4v*)(VT + (ln     ) * 344 + xb);
        short4v v1 = *(const short4v*)(VT + (ln + 16) * 344 + xb);
        O0 = mfma16bf16(v0, P[oi][sl], O0);
        O1 = mfma16bf16(v1, P[oi][sl], O1);
      }
    }
    u32x2 o0, o1;
    o0[0] = pkbf(O0[0]*inv, O0[1]*inv);
    o0[1] = pkbf(O0[2]*inv, O0[3]*inv);
    o1[0] = pkbf(O1[0]*inv, O1[1]*inv);
    o1[1] = pkbf(O1[2]*inv, O1[3]*inv);
    *(u32x2*)(qp + 4 * g)      = o0;
    *(u32x2*)(qp + 16 + 4 * g) = o1;
  }
}

// ---- kernel 3: proj + residual + reg-LN2 + reg-h MLP; 32KB LDS, 4 blk/CU ---
__global__ __launch_bounds__(256, 4) void k_proj_mlp(
    const u16* __restrict__ ao, const u16* __restrict__ wfp,
    const float* __restrict__ projb, const float* __restrict__ x,
    const u16* __restrict__ wf1, const float* __restrict__ b1p,
    const u16* __restrict__ wf2, const float* __restrict__ b2,
    float* __restrict__ yout)
{
  __shared__ __align__(16) char smem[32768];   // bufA @0, bufB @16384
  const int t = threadIdx.x;
  const int w = t >> 6, l = t & 63, lg = l >> 4, ln = l & 15;
  const int P0 = blockIdx.x * 128;
  const int b = P0 >> 16;
  const int pix0 = P0 & 65535;

  auto stage8k = [&](const u16* gsrc, int ldsoff){
    const char* g = (const char*)gsrc;
    int base = w * 2048;
    #pragma unroll
    for (int i = 0; i < 2; ++i){
      int off = base + i * 1024;
      __builtin_amdgcn_global_load_lds(
        (const u32 __attribute__((address_space(1)))*)(g + off + l * 16),
        (u32 __attribute__((address_space(3)))*)(smem + ldsoff + off),
        16, 0, 0);
    }
  };

  stage8k(wfp,          0);
  stage8k(wfp + 4096,   8192);
  stage8k(wfp + 8192,  16384);
  stage8k(wfp + 12288, 24576);

  const int pA = w * 32 + ln;
  const int pB = pA + 16;

  bf16x8 bbA[4], bbB[4];
  #pragma unroll
  for (int kt = 0; kt < 4; ++kt){
    const u16* hb = ao + ((size_t)(b * 4 + kt)) * 2097152ull;
    bbA[kt] = *(const bf16x8*)(hb + (size_t)(pix0 + pA) * 32 + lg * 8);
    bbB[kt] = *(const bf16x8*)(hb + (size_t)(pix0 + pB) * 32 + lg * 8);
  }
  float xrA[8][4], xrB[8][4];
  #pragma unroll
  for (int m = 0; m < 8; ++m){
    int c0 = m * 16 + 4 * lg;
    size_t base = ((size_t)(b * 128 + c0)) * HW + pix0 + pA;
    #pragma unroll
    for (int r = 0; r < 4; ++r){
      xrA[m][r] = x[base + (size_t)r * HW];
      xrB[m][r] = x[base + 16 + (size_t)r * HW];
    }
  }
  __syncthreads();

  f32x4 yvA[8], yvB[8];
  #pragma unroll
  for (int m = 0; m < 8; ++m){ yvA[m] = (f32x4)(0.f); yvB[m] = (f32x4)(0.f); }
  __builtin_amdgcn_s_setprio(1);
  #pragma unroll
  for (int kt = 0; kt < 4; ++kt)
    #pragma unroll
    for (int m = 0; m < 8; ++m){
      int off = (m < 4) ? ((m*4 + kt) << 10) : (16384 + (((m-4)*4 + kt) << 10));
      bf16x8 a = *(const bf16x8*)(smem + off + l * 16);
      yvA[m] = MFMA32(a, bbA[kt], yvA[m]);
      yvB[m] = MFMA32(a, bbB[kt], yvB[m]);
    }
  __builtin_amdgcn_s_setprio(0);
  __syncthreads();
  stage8k(wf1, 0);
  stage8k(wf2, 8192);

  float sA = 0.f, s2A = 0.f, sB = 0.f, s2B = 0.f;
  #pragma unroll
  for (int m = 0; m < 8; ++m){
    int c0 = m * 16 + 4 * lg;
    f32x4 pbv = *(const f32x4*)(projb + c0);
    #pragma unroll
    for (int r = 0; r < 4; ++r){
      float vA = xrA[m][r] + yvA[m][r] + pbv[r];
      float vB = xrB[m][r] + yvB[m][r] + pbv[r];
      yvA[m][r] = vA; yvB[m][r] = vB;
      sA += vA; s2A = fmaf(vA, vA, s2A);
      sB += vB; s2B = fmaf(vB, vB, s2B);
    }
  }
  sA  += __shfl_xor(sA, 16);  sA  += __shfl_xor(sA, 32);
  s2A += __shfl_xor(s2A, 16); s2A += __shfl_xor(s2A, 32);
  sB  += __shfl_xor(sB, 16);  sB  += __shfl_xor(sB, 32);
  s2B += __shfl_xor(s2B, 16); s2B += __shfl_xor(s2B, 32);
  float muA = sA * 0.0078125f;
  float rsA = rsqrtf(s2A * 0.0078125f - muA * muA + 1e-5f);
  float muB = sB * 0.0078125f;
  float rsB = rsqrtf(s2B * 0.0078125f - muB * muB + 1e-5f);

  // normalize via wave-local LDS round-trip (n2w/n2b folded into weights)
  {
    char* wbase = smem + 16384 + w * 4096;
    #pragma unroll
    for (int m = 0; m < 8; ++m){
      int g8 = 2 * m + (lg >> 1);
      u32x2 pk;
      pk[0] = pkbf((yvA[m][0]-muA)*rsA, (yvA[m][1]-muA)*rsA);
      pk[1] = pkbf((yvA[m][2]-muA)*rsA, (yvA[m][3]-muA)*rsA);
      *(u32x2*)(wbase + ln * 256 + ((g8 ^ (ln & 7)) << 4) + ((lg & 1) << 3)) = pk;
    }
    #pragma unroll
    for (int kt = 0; kt < 4; ++kt)
      bbA[kt] = *(const bf16x8*)(wbase + ln * 256 + (((kt*4 + lg) ^ (ln & 7)) << 4));
    #pragma unroll
    for (int m = 0; m < 8; ++m){
      int g8 = 2 * m + (lg >> 1);
      u32x2 pk;
      pk[0] = pkbf((yvB[m][0]-muB)*rsB, (yvB[m][1]-muB)*rsB);
      pk[1] = pkbf((yvB[m][2]-muB)*rsB, (yvB[m][3]-muB)*rsB);
      *(u32x2*)(wbase + ln * 256 + ((g8 ^ (ln & 7)) << 4) + ((lg & 1) << 3)) = pk;
    }
    #pragma unroll
    for (int kt = 0; kt < 4; ++kt)
      bbB[kt] = *(const bf16x8*)(wbase + ln * 256 + (((kt*4 + lg) ^ (ln & 7)) << 4));
  }

  f32x4 acA[8], acB[8];
  #pragma unroll
  for (int m = 0; m < 8; ++m){
    int c0 = m * 16 + 4 * lg;
    f32x4 b2v = *(const f32x4*)(b2 + c0);
    #pragma unroll
    for (int r = 0; r < 4; ++r){
      acA[m][r] = yvA[m][r] + b2v[r];
      acB[m][r] = yvB[m][r] + b2v[r];
    }
  }
  __syncthreads();

  for (int c = 0; c < 16; ++c){
    const int cur = (c & 1) ? 16384 : 0;
    if (c < 15){
      const int nxt = cur ^ 16384;
      stage8k(wf1 + (c + 1) * 4096, nxt);
      stage8k(wf2 + (c + 1) * 4096, nxt + 8192);
    }
    f32x4 hA[2], hB[2];
    hA[0] = (f32x4)(0.f); hA[1] = (f32x4)(0.f);
    hB[0] = (f32x4)(0.f); hB[1] = (f32x4)(0.f);
    __builtin_amdgcn_s_setprio(1);
    #pragma unroll
    for (int kt = 0; kt < 4; ++kt)
      #pragma unroll
      for (int mt = 0; mt < 2; ++mt){
        bf16x8 a = *(const bf16x8*)(smem + cur + ((mt*4 + kt) << 10) + l * 16);
        hA[mt] = MFMA32(a, bbA[kt], hA[mt]);
        hB[mt] = MFMA32(a, bbB[kt], hB[mt]);
      }
    __builtin_amdgcn_s_setprio(0);
    int hb0 = c * 32 + 4 * lg;
    f32x4 b1a = *(const f32x4*)(b1p + hb0);
    f32x4 b1b = *(const f32x4*)(b1p + hb0 + 16);
    bf16x8 hfA, hfB;
    {
      union { u32x4 u; bf16x8 h; } uu;
      uu.u[0] = pkbf(gelu_tanh(hA[0][0]+b1a[0]), gelu_tanh(hA[0][1]+b1a[1]));
      uu.u[1] = pkbf(gelu_tanh(hA[0][2]+b1a[2]), gelu_tanh(hA[0][3]+b1a[3]));
      uu.u[2] = pkbf(gelu_tanh(hA[1][0]+b1b[0]), gelu_tanh(hA[1][1]+b1b[1]));
      uu.u[3] = pkbf(gelu_tanh(hA[1][2]+b1b[2]), gelu_tanh(hA[1][3]+b1b[3]));
      hfA = uu.h;
      uu.u[0] = pkbf(gelu_tanh(hB[0][0]+b1a[0]), gelu_tanh(hB[0][1]+b1a[1]));
      uu.u[1] = pkbf(gelu_tanh(hB[0][2]+b1a[2]), gelu_tanh(hB[0][3]+b1a[3]));
      uu.u[2] = pkbf(gelu_tanh(hB[1][0]+b1b[0]), gelu_tanh(hB[1][1]+b1b[1]));
      uu.u[3] = pkbf(gelu_tanh(hB[1][2]+b1b[2]), gelu_tanh(hB[1][3]+b1b[3]));
      hfB = uu.h;
    }
    __builtin_amdgcn_s_setprio(1);
    #pragma unroll
    for (int m = 0; m < 8; ++m){
      bf16x8 a = *(const bf16x8*)(smem + cur + 8192 + (m << 10) + l * 16);
      acA[m] = MFMA32(a, hfA, acA[m]);
      acB[m] = MFMA32(a, hfB, acB[m]);
    }
    __builtin_amdgcn_s_setprio(0);
    if (c < 15) __syncthreads();
  }

  #pragma unroll
  for (int m = 0; m < 8; ++m){
    int c0 = m * 16 + 4 * lg;
    size_t base = ((size_t)(b * 128 + c0)) * HW + pix0 + pA;
    #pragma unroll
    for (int r = 0; r < 4; ++r){
      yout[base + (size_t)r * HW]      = acA[m][r];
      yout[base + 16 + (size_t)r * HW] = acB[m][r];
    }
  }
}

extern "C" void kernel_launch(void* const* d_in, const int* in_sizes, int n_in,
                              void* d_out, int out_size, void* d_ws, size_t ws_size,
                              hipStream_t stream)
{
  const float* x    = (const float*)d_in[0];
  const float* n1w  = (const float*)d_in[1];
  const float* n1b  = (const float*)d_in[2];
  const float* qkvw = (const float*)d_in[3];
  const float* qkvb = (const float*)d_in[4];
  const float* pw   = (const float*)d_in[5];
  const float* pb   = (const float*)d_in[6];
  const float* n2w  = (const float*)d_in[7];
  const float* n2b  = (const float*)d_in[8];
  const float* w1   = (const float*)d_in[9];
  const float* b1   = (const float*)d_in[10];
  const float* w2   = (const float*)d_in[11];
  const float* b2   = (const float*)d_in[12];

  u16* qkvp = (u16*)d_ws;                  // q/k/v planes, each [b][4][65536][32] = 128 MB
  u16* qbuf = qkvp;                        // q plane doubles as attention output
  u16* kbuf = qkvp + 67108864ull;
  u16* vbuf = qkvp + 134217728ull;
  u16* wf   = qkvp + 201326592ull;         // packed dense weights + folded biases
  u16* wfq = wf;
  u16* wfp = wf + 49152;
  u16* wf1 = wf + 65536;
  u16* wf2 = wf + 131072;
  float* bias = (float*)(wf + 196608);     // bq [0..383], b1p [384..895]
  float* y = (float*)d_out;

  k_pack<<<388, 256, 0, stream>>>(qkvw, pw, w1, w2, n1w, n1b, n2w, n2b, qkvb, b1, wf);
  k_ln_qkv<<<4096, 256, 0, stream>>>(x, wfq, bias, qkvp);
  k_attn<<<16384, 256, 0, stream>>>(qbuf, kbuf, vbuf);
  k_proj_mlp<<<4096, 256, 0, stream>>>(qbuf, wfp, pb, x, wf1, bias + 384, wf2, b2, y);
}

// Round 17
// 615.351 us; speedup vs baseline: 1.2128x; 1.2128x over previous
//
#include <hip/hip_runtime.h>
#include <hip/hip_bf16.h>

typedef unsigned short u16;
typedef unsigned int u32;
typedef __attribute__((ext_vector_type(4))) u32 u32x4;
typedef __attribute__((ext_vector_type(2))) u32 u32x2;
typedef __attribute__((ext_vector_type(8))) __bf16 bf16x8;
typedef __attribute__((ext_vector_type(4))) float f32x4;
typedef __attribute__((ext_vector_type(4))) short short4v;

#define HW 65536
#define MFMA32(a, b, c) __builtin_amdgcn_mfma_f32_16x16x32_bf16((a), (b), (c), 0, 0, 0)

__device__ __forceinline__ u16 f2bf(float f){
  union { u32 i; float f; } v; v.f = f;
  u32 r = v.i + 0x7fffu + ((v.i >> 16) & 1u);
  return (u16)(r >> 16);
}
__device__ __forceinline__ u32 pkbf(float a, float b){
  __bf16 lo = (__bf16)a, hi = (__bf16)b;
  u16 ulo = __builtin_bit_cast(u16, lo);
  u16 uhi = __builtin_bit_cast(u16, hi);
  return (u32)ulo | ((u32)uhi << 16);
}
__device__ __forceinline__ float rcpf(float x){
#if __has_builtin(__builtin_amdgcn_rcpf)
  return __builtin_amdgcn_rcpf(x);
#else
  return 1.0f / x;
#endif
}
__device__ __forceinline__ float gelu_tanh(float v){
  float t = v * v;
  float u = fmaf(0.044715f * t, v, v);
  float z = 1.5957691216057308f * u;
  float e = __expf(-z);
  return v * rcpf(1.0f + e);
}

__device__ __forceinline__ f32x4 mfma16bf16(short4v a, short4v b, f32x4 c){
#if __has_builtin(__builtin_amdgcn_mfma_f32_16x16x16bf16_1k)
  return __builtin_amdgcn_mfma_f32_16x16x16bf16_1k(a, b, c, 0, 0, 0);
#else
  f32x4 d;
  asm volatile("v_mfma_f32_16x16x16_bf16 %0, %1, %2, %3"
               : "=v"(d) : "v"(a), "v"(b), "v"(c));
  return d;
#endif
}

// ---- pack weights into DENSE (1KB) bf16 MFMA A-fragment tiles --------------
// LN folds: qkv tiles carry n1w (q rows also carry hd^-0.5); w1 carries n2w.
// Folded biases (f32): bq[o] = (qkvb[o] + Wqkv.n1b)·qs, b1p[h] = b1[h] + W1.n2b
__global__ __launch_bounds__(256) void k_pack(
    const float* __restrict__ qkvw, const float* __restrict__ projw,
    const float* __restrict__ w1, const float* __restrict__ w2,
    const float* __restrict__ n1w, const float* __restrict__ n1b,
    const float* __restrict__ n2w, const float* __restrict__ n2b,
    const float* __restrict__ qkvb, const float* __restrict__ b1,
    u16* __restrict__ wf)
{
  const float S = 0.17677669529663687f;   // HEAD_DIM^-0.5
  int tile = blockIdx.x;
  int t = threadIdx.x;
  float* bias = (float*)(wf + 196608);
  if (tile >= 384){
    if (tile < 386){
      int o = (tile - 384) * 256 + t;
      if (o < 384){
        float s = qkvb[o];
        for (int c = 0; c < 128; ++c) s = fmaf(qkvw[(size_t)o * 128 + c], n1b[c], s);
        bias[o] = s * (o < 128 ? S : 1.f);
      }
    } else {
      int h = (tile - 386) * 256 + t;
      float s = b1[h];
      for (int c = 0; c < 128; ++c) s = fmaf(w1[(size_t)h * 128 + c], n2b[c], s);
      bias[384 + h] = s;
    }
    return;
  }
  int l = t >> 1, half = t & 1;
  if (l >= 64) return;
  int lg = l >> 4;
  if (tile >= 256){
    int ti = tile - 256;
    int hp = ti >> 3, m = ti & 7;
    int row = m * 16 + (l & 15);
    u16 o[4];
    #pragma unroll
    for (int j = 0; j < 4; ++j){
      int s = half * 4 + j;
      int kloc = (s < 4) ? (4 * lg + s) : (16 + 4 * lg + (s - 4));
      o[j] = f2bf(w2[(size_t)row * 512 + hp * 32 + kloc]);
    }
    u32x2 v; v[0] = (u32)o[0] | ((u32)o[1] << 16); v[1] = (u32)o[2] | ((u32)o[3] << 16);
    *(u32x2*)(wf + 131072 + ti * 512 + l * 8 + half * 4) = v;
    return;
  }
  const float* W; int base, ti; int mode;
  if (tile < 96)       { W = qkvw; base = 0;     ti = tile;      mode = 0; }
  else if (tile < 128) { W = projw; base = 49152; ti = tile - 96; mode = 1; }
  else                 { W = w1;   base = 65536; ti = tile - 128; mode = 2; }
  int mt = ti / 4, kt = ti % 4;
  int r0 = half * 4;
  int m = mt * 16 + (l & 15);
  int kb = kt * 32 + 8 * lg + r0;
  u16 o[4];
  #pragma unroll
  for (int j = 0; j < 4; ++j){
    float wv = W[(size_t)m * 128 + kb + j];
    if (mode == 0) wv *= n1w[kb + j] * (m < 128 ? S : 1.f);
    if (mode == 2) wv *= n2w[kb + j];
    o[j] = f2bf(wv);
  }
  u32x2 v; v[0] = (u32)o[0] | ((u32)o[1] << 16); v[1] = (u32)o[2] | ((u32)o[3] << 16);
  *(u32x2*)(wf + base + ti * 512 + l * 8 + r0) = v;
}

// ---- kernel 1: channel-LN + QKV GEMM; 128-px blocks, staged weights --------
__global__ __launch_bounds__(256, 3) void k_ln_qkv(
    const float* __restrict__ x, const u16* __restrict__ wfq,
    const float* __restrict__ bq, u16* __restrict__ qkvp)
{
  __shared__ __align__(16) char smem[32768];   // bufA @0, bufB @16384
  const int t = threadIdx.x;
  const int w = t >> 6, l = t & 63, lg = l >> 4, ln = l & 15;
  const int P0 = blockIdx.x * 128;
  const int b = P0 >> 16;
  const int pix0 = P0 & 65535;

  auto stage8k = [&](const u16* gsrc, int ldsoff){
    const char* g = (const char*)gsrc;
    int base = w * 2048;
    #pragma unroll
    for (int i = 0; i < 2; ++i){
      int off = base + i * 1024;
      __builtin_amdgcn_global_load_lds(
        (const u32 __attribute__((address_space(1)))*)(g + off + l * 16),
        (u32 __attribute__((address_space(3)))*)(smem + ldsoff + off),
        16, 0, 0);
    }
  };

  stage8k(wfq, 0);
  stage8k(wfq + 4096, 8192);

  const int pA = w * 32 + ln, pB = pA + 16;

  float xA[8][4], xB[8][4];
  float sA = 0.f, s2A = 0.f, sB = 0.f, s2B = 0.f;
  #pragma unroll
  for (int m = 0; m < 8; ++m){
    int c0 = m * 16 + 4 * lg;
    size_t base = ((size_t)(b * 128 + c0)) * HW + pix0 + pA;
    #pragma unroll
    for (int r = 0; r < 4; ++r){
      float vA = x[base + (size_t)r * HW];
      float vB = x[base + 16 + (size_t)r * HW];
      xA[m][r] = vA; xB[m][r] = vB;
      sA += vA; s2A = fmaf(vA, vA, s2A);
      sB += vB; s2B = fmaf(vB, vB, s2B);
    }
  }
  sA  += __shfl_xor(sA, 16);  sA  += __shfl_xor(sA, 32);
  s2A += __shfl_xor(s2A, 16); s2A += __shfl_xor(s2A, 32);
  sB  += __shfl_xor(sB, 16);  sB  += __shfl_xor(sB, 32);
  s2B += __shfl_xor(s2B, 16); s2B += __shfl_xor(s2B, 32);
  float muA = sA * 0.0078125f;
  float rsA = rsqrtf(s2A * 0.0078125f - muA * muA + 1e-5f);
  float muB = sB * 0.0078125f;
  float rsB = rsqrtf(s2B * 0.0078125f - muB * muB + 1e-5f);

  bf16x8 bbA[4], bbB[4];
  {
    char* wbase = smem + 16384 + w * 4096;
    #pragma unroll
    for (int m = 0; m < 8; ++m){
      int g8 = 2 * m + (lg >> 1);
      u32x2 pk;
      pk[0] = pkbf((xA[m][0]-muA)*rsA, (xA[m][1]-muA)*rsA);
      pk[1] = pkbf((xA[m][2]-muA)*rsA, (xA[m][3]-muA)*rsA);
      *(u32x2*)(wbase + ln * 256 + ((g8 ^ (ln & 7)) << 4) + ((lg & 1) << 3)) = pk;
    }
    #pragma unroll
    for (int kt = 0; kt < 4; ++kt)
      bbA[kt] = *(const bf16x8*)(wbase + ln * 256 + (((kt*4 + lg) ^ (ln & 7)) << 4));
    #pragma unroll
    for (int m = 0; m < 8; ++m){
      int g8 = 2 * m + (lg >> 1);
      u32x2 pk;
      pk[0] = pkbf((xB[m][0]-muB)*rsB, (xB[m][1]-muB)*rsB);
      pk[1] = pkbf((xB[m][2]-muB)*rsB, (xB[m][3]-muB)*rsB);
      *(u32x2*)(wbase + ln * 256 + ((g8 ^ (ln & 7)) << 4) + ((lg & 1) << 3)) = pk;
    }
    #pragma unroll
    for (int kt = 0; kt < 4; ++kt)
      bbB[kt] = *(const bf16x8*)(wbase + ln * 256 + (((kt*4 + lg) ^ (ln & 7)) << 4));
  }
  __syncthreads();

  for (int c = 0; c < 6; ++c){
    const int cur = (c & 1) ? 16384 : 0;
    if (c < 5){
      const int nxt = cur ^ 16384;
      stage8k(wfq + (c + 1) * 8192, nxt);
      stage8k(wfq + (c + 1) * 8192 + 4096, nxt + 8192);
    }
    #pragma unroll
    for (int mt = 0; mt < 4; ++mt){
      f32x4 dA = (f32x4)(0.f), dB = (f32x4)(0.f);
      #pragma unroll
      for (int kt = 0; kt < 4; ++kt){
        bf16x8 a = *(const bf16x8*)(smem + cur + ((mt*4 + kt) << 10) + l * 16);
        dA = MFMA32(a, bbA[kt], dA);
        dB = MFMA32(a, bbB[kt], dB);
      }
      int o0 = c * 64 + mt * 16 + 4 * lg;
      f32x4 bqv = *(const f32x4*)(bq + o0);
      u32x2 vA, vB;
      vA[0] = pkbf(dA[0]+bqv[0], dA[1]+bqv[1]);
      vA[1] = pkbf(dA[2]+bqv[2], dA[3]+bqv[3]);
      vB[0] = pkbf(dB[0]+bqv[0], dB[1]+bqv[1]);
      vB[1] = pkbf(dB[2]+bqv[2], dB[3]+bqv[3]);
      u16* plane = qkvp + (size_t)(o0 >> 7) * 67108864ull;
      int hh = (o0 >> 5) & 3;
      int sub = o0 & 31;
      size_t pbase = ((size_t)(b * 4 + hh)) * 65536 + pix0;
      *(u32x2*)(plane + (pbase + pA) * 32 + sub) = vA;
      *(u32x2*)(plane + (pbase + pB) * 32 + sub) = vB;
    }
    if (c < 5) __syncthreads();
  }
}

// ---- kernel 2: 7x7 local attention via MFMA; 16x8 tiles (3 blocks/CU) ------
__global__ __launch_bounds__(256, 3) void k_attn(
    u16* qbuf, const u16* __restrict__ kbuf, const u16* __restrict__ vbuf)
{
  __shared__ __align__(16) u16 Klds[4 * 320 * 8];    // [chgrp][pix 14x22 -> 320][8ch]
  __shared__ __align__(16) u16 VT[32 * 344 + 8];     // [ch][14 rows x 24 pad, stride 344]
  const int t = threadIdx.x;
  const int blk = ((blockIdx.x & 7) << 11) | (blockIdx.x >> 3);
  const int tx16 = blk & 15, ty = (blk >> 4) & 31;
  const int h = (blk >> 9) & 3, b = blk >> 11;
  const int y0 = ty * 8, x0 = tx16 * 16;
  const int bh = b * 4 + h;
  const u16* kg = kbuf + (size_t)bh * 65536 * 32;
  const u16* vg = vbuf + (size_t)bh * 65536 * 32;

  for (int i = t; i < 1377; i += 256) ((u32x4*)VT)[i] = (u32x4){0u,0u,0u,0u};
  __syncthreads();

  for (int pix = t; pix < 308; pix += 256){
    int yy = pix / 22, xx = pix - yy * 22;
    int gy = y0 + yy - 3, gx = x0 + xx - 3;
    bool ok = (gy >= 0 && gy < 256 && gx >= 0 && gx < 256);
    u32x4 kv[4], vv[4];
    #pragma unroll
    for (int j = 0; j < 4; ++j){ kv[j] = (u32x4){0u,0u,0u,0u}; vv[j] = (u32x4){0u,0u,0u,0u}; }
    if (ok){
      size_t gb = ((size_t)(gy * 256 + gx)) * 32;
      #pragma unroll
      for (int j = 0; j < 4; ++j){
        kv[j] = *(const u32x4*)(kg + gb + j * 8);
        vv[j] = *(const u32x4*)(vg + gb + j * 8);
      }
    }
    #pragma unroll
    for (int j = 0; j < 4; ++j)
      *(u32x4*)(Klds + (j * 320 + pix) * 8) = kv[j];
    int vb = yy * 24 + xx;
    #pragma unroll
    for (int j = 0; j < 4; ++j)
      #pragma unroll
      for (int ww = 0; ww < 4; ++ww){
        int c = j * 8 + ww * 2;
        VT[(c    ) * 344 + vb] = (u16)(vv[j][ww] & 0xffffu);
        VT[(c + 1) * 344 + vb] = (u16)(vv[j][ww] >> 16);
      }
  }
  __syncthreads();

  const int l = t & 63, w = t >> 6;
  const int ln = l & 15, g = l >> 4;

  bool mk[2][4];
  #pragma unroll
  for (int sl = 0; sl < 2; ++sl)
    #pragma unroll
    for (int r = 0; r < 4; ++r)
      mk[sl][r] = ((unsigned)(sl * 16 + g * 4 + r - ln)) <= 6u;

  for (int rt = 0; rt < 2; ++rt){
    int yl = rt * 4 + w;
    int qpix = (y0 + yl) * 256 + x0 + ln;
    u16* qp = qbuf + ((size_t)bh * 65536 + qpix) * 32;
    bf16x8 qf = *(const bf16x8*)(qp + g * 8);

    f32x4 S[7][2];
    #pragma unroll
    for (int oi = 0; oi < 7; ++oi){
      int rowb = (yl + oi) * 22;
      #pragma unroll
      for (int sl = 0; sl < 2; ++sl){
        bf16x8 kf = *(const bf16x8*)(Klds + (g * 320 + rowb + sl * 16 + ln) * 8);
        f32x4 z = (f32x4)(0.f);
        S[oi][sl] = MFMA32(kf, qf, z);
      }
    }
    float m = -3e38f;
    #pragma unroll
    for (int oi = 0; oi < 7; ++oi)
      #pragma unroll
      for (int sl = 0; sl < 2; ++sl)
        #pragma unroll
        for (int r = 0; r < 4; ++r){
          float v = mk[sl][r] ? S[oi][sl][r] : -3e38f;
          S[oi][sl][r] = v;
          m = fmaxf(m, v);
        }
    m = fmaxf(m, __shfl_xor(m, 16));
    m = fmaxf(m, __shfl_xor(m, 32));
    float sum = 0.f;
    #pragma unroll
    for (int oi = 0; oi < 7; ++oi)
      #pragma unroll
      for (int sl = 0; sl < 2; ++sl)
        #pragma unroll
        for (int r = 0; r < 4; ++r){
          float e = __expf(S[oi][sl][r] - m);
          S[oi][sl][r] = e;
          sum += e;
        }
    sum += __shfl_xor(sum, 16);
    sum += __shfl_xor(sum, 32);
    float inv = rcpf(sum);

    short4v P[7][2];
    #pragma unroll
    for (int oi = 0; oi < 7; ++oi)
      #pragma unroll
      for (int sl = 0; sl < 2; ++sl){
        union { u32x2 u; short4v s; } cv;
        cv.u[0] = pkbf(S[oi][sl][0], S[oi][sl][1]);
        cv.u[1] = pkbf(S[oi][sl][2], S[oi][sl][3]);
        P[oi][sl] = cv.s;
      }

    f32x4 O0 = (f32x4)(0.f), O1 = (f32x4)(0.f);
    #pragma unroll
    for (int oi = 0; oi < 7; ++oi){
      int rowE = (yl + oi) * 24;
      #pragma unroll
      for (int sl = 0; sl < 2; ++sl){
        int xb = rowE + sl * 16 + 4 * g;
        short4v v0 = *(const short4v*)(VT + (ln     ) * 344 + xb);
        short4v v1 = *(const short4v*)(VT + (ln + 16) * 344 + xb);
        O0 = mfma16bf16(v0, P[oi][sl], O0);
        O1 = mfma16bf16(v1, P[oi][sl], O1);
      }
    }
    u32x2 o0, o1;
    o0[0] = pkbf(O0[0]*inv, O0[1]*inv);
    o0[1] = pkbf(O0[2]*inv, O0[3]*inv);
    o1[0] = pkbf(O1[0]*inv, O1[1]*inv);
    o1[1] = pkbf(O1[2]*inv, O1[3]*inv);
    *(u32x2*)(qp + 4 * g)      = o0;
    *(u32x2*)(qp + 16 + 4 * g) = o1;
  }
}

// ---- kernel 3: proj + residual + reg-LN2 + reg-h MLP; 32KB LDS, setprio ----
__global__ __launch_bounds__(256, 3) void k_proj_mlp(
    const u16* __restrict__ ao, const u16* __restrict__ wfp,
    const float* __restrict__ projb, const float* __restrict__ x,
    const u16* __restrict__ wf1, const float* __restrict__ b1p,
    const u16* __restrict__ wf2, const float* __restrict__ b2,
    float* __restrict__ yout)
{
  __shared__ __align__(16) char smem[32768];   // bufA @0, bufB @16384
  const int t = threadIdx.x;
  const int w = t >> 6, l = t & 63, lg = l >> 4, ln = l & 15;
  const int P0 = blockIdx.x * 128;
  const int b = P0 >> 16;
  const int pix0 = P0 & 65535;

  auto stage8k = [&](const u16* gsrc, int ldsoff){
    const char* g = (const char*)gsrc;
    int base = w * 2048;
    #pragma unroll
    for (int i = 0; i < 2; ++i){
      int off = base + i * 1024;
      __builtin_amdgcn_global_load_lds(
        (const u32 __attribute__((address_space(1)))*)(g + off + l * 16),
        (u32 __attribute__((address_space(3)))*)(smem + ldsoff + off),
        16, 0, 0);
    }
  };

  stage8k(wfp,          0);
  stage8k(wfp + 4096,   8192);
  stage8k(wfp + 8192,  16384);
  stage8k(wfp + 12288, 24576);

  const int pA = w * 32 + ln;
  const int pB = pA + 16;

  bf16x8 bbA[4], bbB[4];
  #pragma unroll
  for (int kt = 0; kt < 4; ++kt){
    const u16* hb = ao + ((size_t)(b * 4 + kt)) * 2097152ull;
    bbA[kt] = *(const bf16x8*)(hb + (size_t)(pix0 + pA) * 32 + lg * 8);
    bbB[kt] = *(const bf16x8*)(hb + (size_t)(pix0 + pB) * 32 + lg * 8);
  }
  float xrA[8][4], xrB[8][4];
  #pragma unroll
  for (int m = 0; m < 8; ++m){
    int c0 = m * 16 + 4 * lg;
    size_t base = ((size_t)(b * 128 + c0)) * HW + pix0 + pA;
    #pragma unroll
    for (int r = 0; r < 4; ++r){
      xrA[m][r] = x[base + (size_t)r * HW];
      xrB[m][r] = x[base + 16 + (size_t)r * HW];
    }
  }
  __syncthreads();

  f32x4 yvA[8], yvB[8];
  #pragma unroll
  for (int m = 0; m < 8; ++m){ yvA[m] = (f32x4)(0.f); yvB[m] = (f32x4)(0.f); }
  __builtin_amdgcn_s_setprio(1);
  #pragma unroll
  for (int kt = 0; kt < 4; ++kt)
    #pragma unroll
    for (int m = 0; m < 8; ++m){
      int off = (m < 4) ? ((m*4 + kt) << 10) : (16384 + (((m-4)*4 + kt) << 10));
      bf16x8 a = *(const bf16x8*)(smem + off + l * 16);
      yvA[m] = MFMA32(a, bbA[kt], yvA[m]);
      yvB[m] = MFMA32(a, bbB[kt], yvB[m]);
    }
  __builtin_amdgcn_s_setprio(0);
  __syncthreads();
  stage8k(wf1, 0);
  stage8k(wf2, 8192);

  float sA = 0.f, s2A = 0.f, sB = 0.f, s2B = 0.f;
  #pragma unroll
  for (int m = 0; m < 8; ++m){
    int c0 = m * 16 + 4 * lg;
    f32x4 pbv = *(const f32x4*)(projb + c0);
    #pragma unroll
    for (int r = 0; r < 4; ++r){
      float vA = xrA[m][r] + yvA[m][r] + pbv[r];
      float vB = xrB[m][r] + yvB[m][r] + pbv[r];
      yvA[m][r] = vA; yvB[m][r] = vB;
      sA += vA; s2A = fmaf(vA, vA, s2A);
      sB += vB; s2B = fmaf(vB, vB, s2B);
    }
  }
  sA  += __shfl_xor(sA, 16);  sA  += __shfl_xor(sA, 32);
  s2A += __shfl_xor(s2A, 16); s2A += __shfl_xor(s2A, 32);
  sB  += __shfl_xor(sB, 16);  sB  += __shfl_xor(sB, 32);
  s2B += __shfl_xor(s2B, 16); s2B += __shfl_xor(s2B, 32);
  float muA = sA * 0.0078125f;
  float rsA = rsqrtf(s2A * 0.0078125f - muA * muA + 1e-5f);
  float muB = sB * 0.0078125f;
  float rsB = rsqrtf(s2B * 0.0078125f - muB * muB + 1e-5f);

  // normalize via wave-local LDS round-trip (n2w/n2b folded into weights)
  {
    char* wbase = smem + 16384 + w * 4096;
    #pragma unroll
    for (int m = 0; m < 8; ++m){
      int g8 = 2 * m + (lg >> 1);
      u32x2 pk;
      pk[0] = pkbf((yvA[m][0]-muA)*rsA, (yvA[m][1]-muA)*rsA);
      pk[1] = pkbf((yvA[m][2]-muA)*rsA, (yvA[m][3]-muA)*rsA);
      *(u32x2*)(wbase + ln * 256 + ((g8 ^ (ln & 7)) << 4) + ((lg & 1) << 3)) = pk;
    }
    #pragma unroll
    for (int kt = 0; kt < 4; ++kt)
      bbA[kt] = *(const bf16x8*)(wbase + ln * 256 + (((kt*4 + lg) ^ (ln & 7)) << 4));
    #pragma unroll
    for (int m = 0; m < 8; ++m){
      int g8 = 2 * m + (lg >> 1);
      u32x2 pk;
      pk[0] = pkbf((yvB[m][0]-muB)*rsB, (yvB[m][1]-muB)*rsB);
      pk[1] = pkbf((yvB[m][2]-muB)*rsB, (yvB[m][3]-muB)*rsB);
      *(u32x2*)(wbase + ln * 256 + ((g8 ^ (ln & 7)) << 4) + ((lg & 1) << 3)) = pk;
    }
    #pragma unroll
    for (int kt = 0; kt < 4; ++kt)
      bbB[kt] = *(const bf16x8*)(wbase + ln * 256 + (((kt*4 + lg) ^ (ln & 7)) << 4));
  }

  f32x4 acA[8], acB[8];
  #pragma unroll
  for (int m = 0; m < 8; ++m){
    int c0 = m * 16 + 4 * lg;
    f32x4 b2v = *(const f32x4*)(b2 + c0);
    #pragma unroll
    for (int r = 0; r < 4; ++r){
      acA[m][r] = yvA[m][r] + b2v[r];
      acB[m][r] = yvB[m][r] + b2v[r];
    }
  }
  __syncthreads();

  for (int c = 0; c < 16; ++c){
    const int cur = (c & 1) ? 16384 : 0;
    if (c < 15){
      const int nxt = cur ^ 16384;
      stage8k(wf1 + (c + 1) * 4096, nxt);
      stage8k(wf2 + (c + 1) * 4096, nxt + 8192);
    }
    f32x4 hA[2], hB[2];
    hA[0] = (f32x4)(0.f); hA[1] = (f32x4)(0.f);
    hB[0] = (f32x4)(0.f); hB[1] = (f32x4)(0.f);
    __builtin_amdgcn_s_setprio(1);
    #pragma unroll
    for (int kt = 0; kt < 4; ++kt)
      #pragma unroll
      for (int mt = 0; mt < 2; ++mt){
        bf16x8 a = *(const bf16x8*)(smem + cur + ((mt*4 + kt) << 10) + l * 16);
        hA[mt] = MFMA32(a, bbA[kt], hA[mt]);
        hB[mt] = MFMA32(a, bbB[kt], hB[mt]);
      }
    __builtin_amdgcn_s_setprio(0);
    int hb0 = c * 32 + 4 * lg;
    f32x4 b1a = *(const f32x4*)(b1p + hb0);
    f32x4 b1b = *(const f32x4*)(b1p + hb0 + 16);
    bf16x8 hfA, hfB;
    {
      union { u32x4 u; bf16x8 h; } uu;
      uu.u[0] = pkbf(gelu_tanh(hA[0][0]+b1a[0]), gelu_tanh(hA[0][1]+b1a[1]));
      uu.u[1] = pkbf(gelu_tanh(hA[0][2]+b1a[2]), gelu_tanh(hA[0][3]+b1a[3]));
      uu.u[2] = pkbf(gelu_tanh(hA[1][0]+b1b[0]), gelu_tanh(hA[1][1]+b1b[1]));
      uu.u[3] = pkbf(gelu_tanh(hA[1][2]+b1b[2]), gelu_tanh(hA[1][3]+b1b[3]));
      hfA = uu.h;
      uu.u[0] = pkbf(gelu_tanh(hB[0][0]+b1a[0]), gelu_tanh(hB[0][1]+b1a[1]));
      uu.u[1] = pkbf(gelu_tanh(hB[0][2]+b1a[2]), gelu_tanh(hB[0][3]+b1a[3]));
      uu.u[2] = pkbf(gelu_tanh(hB[1][0]+b1b[0]), gelu_tanh(hB[1][1]+b1b[1]));
      uu.u[3] = pkbf(gelu_tanh(hB[1][2]+b1b[2]), gelu_tanh(hB[1][3]+b1b[3]));
      hfB = uu.h;
    }
    __builtin_amdgcn_s_setprio(1);
    #pragma unroll
    for (int m = 0; m < 8; ++m){
      bf16x8 a = *(const bf16x8*)(smem + cur + 8192 + (m << 10) + l * 16);
      acA[m] = MFMA32(a, hfA, acA[m]);
      acB[m] = MFMA32(a, hfB, acB[m]);
    }
    __builtin_amdgcn_s_setprio(0);
    if (c < 15) __syncthreads();
  }

  #pragma unroll
  for (int m = 0; m < 8; ++m){
    int c0 = m * 16 + 4 * lg;
    size_t base = ((size_t)(b * 128 + c0)) * HW + pix0 + pA;
    #pragma unroll
    for (int r = 0; r < 4; ++r){
      yout[base + (size_t)r * HW]      = acA[m][r];
      yout[base + 16 + (size_t)r * HW] = acB[m][r];
    }
  }
}

extern "C" void kernel_launch(void* const* d_in, const int* in_sizes, int n_in,
                              void* d_out, int out_size, void* d_ws, size_t ws_size,
                              hipStream_t stream)
{
  const float* x    = (const float*)d_in[0];
  const float* n1w  = (const float*)d_in[1];
  const float* n1b  = (const float*)d_in[2];
  const float* qkvw = (const float*)d_in[3];
  const float* qkvb = (const float*)d_in[4];
  const float* pw   = (const float*)d_in[5];
  const float* pb   = (const float*)d_in[6];
  const float* n2w  = (const float*)d_in[7];
  const float* n2b  = (const float*)d_in[8];
  const float* w1   = (const float*)d_in[9];
  const float* b1   = (const float*)d_in[10];
  const float* w2   = (const float*)d_in[11];
  const float* b2   = (const float*)d_in[12];

  u16* qkvp = (u16*)d_ws;                  // q/k/v planes, each [b][4][65536][32] = 128 MB
  u16* qbuf = qkvp;                        // q plane doubles as attention output
  u16* kbuf = qkvp + 67108864ull;
  u16* vbuf = qkvp + 134217728ull;
  u16* wf   = qkvp + 201326592ull;         // packed dense weights + folded biases
  u16* wfq = wf;
  u16* wfp = wf + 49152;
  u16* wf1 = wf + 65536;
  u16* wf2 = wf + 131072;
  float* bias = (float*)(wf + 196608);     // bq [0..383], b1p [384..895]
  float* y = (float*)d_out;

  k_pack<<<388, 256, 0, stream>>>(qkvw, pw, w1, w2, n1w, n1b, n2w, n2b, qkvb, b1, wf);
  k_ln_qkv<<<4096, 256, 0, stream>>>(x, wfq, bias, qkvp);
  k_attn<<<16384, 256, 0, stream>>>(qbuf, kbuf, vbuf);
  k_proj_mlp<<<4096, 256, 0, stream>>>(qbuf, wfp, pb, x, wf1, bias + 384, wf2, b2, y);
}